// Round 15
// baseline (122.115 us; speedup 1.0000x reference)
//
#include <hip/hip_runtime.h>
#include <hip/hip_bf16.h>

// features (16384,128) fp32; B=8192; D=128. TEMP=1; BETA=0.5; ALPHA=0.5; GAMMA=0.5.
// out = positive_loss + nl_a + nl_b + 0.5*(s_a + s_b), scalar fp32.
//
// Ladder (neg_kernel): R8 both-LDS = 54.3us (VALU 47%, 2blk/CU); R9 no-LDS = 108us
// (latency-serialized); R10 B-LDS half-tile = 81.7us (2x blocks); R12 B-LDS full-tile
// (512,8) = 69us with 21MB scratch-spill writes (VGPR forced to 32).
// R13: B-only LDS (32KB) + A held in regs (8 x short8, prefetched pre-barrier),
// (512,4) -> VGPR cap 128 (no spill), single-accumulator cubic epilogue
// acc += s * cubic(s) with coefficients absorbing exp-Taylor, 1/B and GAMMA.

typedef __attribute__((ext_vector_type(8))) short short8;
typedef __attribute__((ext_vector_type(4))) float float4v;

#define NROWS 16384
#define BHALF 8192
#define D 128
#define NT 64            // 8192/128 tiles per dim
#define NPAIRS 2080      // NT*(NT+1)/2
#define NACC 64
#define NPART 256

// cubic(s) = exp(s/2)/B + 0.5 (Taylor-3): c0..c3
#define C0 0.5001220703125f      // 0.5 + 1/8192
#define C1 6.103515625e-5f       // 1/(2*8192)
#define C2 1.52587890625e-5f     // 1/(8*8192)
#define C3 2.5431315104e-6f      // 1/(48*8192)

__device__ __forceinline__ unsigned short f2bf(float x) {
    unsigned int u = __float_as_uint(x);
    u += 0x7fffu + ((u >> 16) & 1u);   // RNE
    return (unsigned short)(u >> 16);
}

// ---- Kernel 1: convert + row norms + positive loss (batched loads) ----
__global__ __launch_bounds__(512)
void prep_pos_kernel(const float* __restrict__ f,
                     unsigned short* __restrict__ xbf,
                     float* __restrict__ xx,
                     float* __restrict__ part,
                     float* __restrict__ negacc) {
    __shared__ float red[8];
    const int wave = threadIdx.x >> 6, lane = threadIdx.x & 63;
    const int gw = blockIdx.x * 8 + wave;   // 0..2047
    float posAcc = 0.0f;

    // batch all 8 HBM loads -> single latency exposure
    float2 av[4], bv[4];
    #pragma unroll
    for (int p = 0; p < 4; ++p) {
        const int i = gw + p * 2048;
        av[p] = *reinterpret_cast<const float2*>(f + (size_t)i * D + lane * 2);
        bv[p] = *reinterpret_cast<const float2*>(f + (size_t)(i + BHALF) * D + lane * 2);
    }

    #pragma unroll
    for (int p = 0; p < 4; ++p) {
        const int i = gw + p * 2048;
        ushort2 sa2, sb2;
        sa2.x = f2bf(av[p].x); sa2.y = f2bf(av[p].y);
        sb2.x = f2bf(bv[p].x); sb2.y = f2bf(bv[p].y);
        *reinterpret_cast<ushort2*>(xbf + (size_t)i * D + lane * 2) = sa2;
        *reinterpret_cast<ushort2*>(xbf + (size_t)(i + BHALF) * D + lane * 2) = sb2;
        float sa = av[p].x * av[p].x + av[p].y * av[p].y;
        float sb = bv[p].x * bv[p].x + bv[p].y * bv[p].y;
        float dx = av[p].x - bv[p].x, dy = av[p].y - bv[p].y;
        float sp = dx * dx + dy * dy;
        #pragma unroll
        for (int off = 32; off; off >>= 1) {
            sa += __shfl_down(sa, off, 64);
            sb += __shfl_down(sb, off, 64);
            sp += __shfl_down(sp, off, 64);
        }
        if (lane == 0) {
            xx[i] = sa;
            xx[i + BHALF] = sb;
            float ps = 1.0f / (sp + 1.0f);
            posAcc += (ps - 10.0f) * (ps - 10.0f) - ps;   // -2*ALPHA*ps = -ps
        }
    }
    if (lane == 0) red[wave] = posAcc;
    if (blockIdx.x == 0 && threadIdx.x < NACC) negacc[threadIdx.x] = 0.0f;
    __syncthreads();
    if (threadIdx.x == 0) {
        float s = 0.0f;
        #pragma unroll
        for (int w = 0; w < 8; ++w) s += red[w];
        part[blockIdx.x] = s;                 // raw sum; /B applied in finish
    }
}

// ---- Kernel 2: 128x128 tiles, B-only LDS, A in registers ----
// grid = (NPAIRS, 2). 512 threads = 8 waves (4 row x 2 col); per-wave 32x64 out.
__global__ __launch_bounds__(512, 4)
void neg_kernel(const unsigned short* __restrict__ xbf,
                const float* __restrict__ xx,
                float* __restrict__ negacc) {
    __shared__ unsigned short lB[128 * 128];  // 32 KiB, XOR-swizzled 16B units
    __shared__ float red[8];

    const int t = threadIdx.x;
    const int mat = blockIdx.y;
    const int moff = mat * BHALF;

    // decode upper-triangular pair index -> (tbi, tbj), tbi <= tbj
    int rem = blockIdx.x, bi = 0;
    while (rem >= NT - bi) { rem -= NT - bi; ++bi; }
    const int tbi = bi, tbj = bi + rem;

    const int wave = t >> 6, lane = t & 63;
    const int wr = wave >> 1, wc = wave & 1;      // 4 x 2 wave grid
    const int l15 = lane & 15, g = lane >> 4;

    // ---- stage B tile (tbj) via global_load_lds; swizzle on GLOBAL source ----
    {
        const char* gbase = (const char*)(xbf + (size_t)(moff + tbj * 128) * D);
        #pragma unroll
        for (int p = 0; p < 4; ++p) {
            const int c = p * 512 + t;            // 16B-unit index 0..2047
            const int row = c >> 4, col16 = c & 15;
            const int gb = row * 256 + ((col16 * 16) ^ ((row & 7) << 4));
            const unsigned ldsoff = (unsigned)(p * 512 + wave * 64) * 16;  // wave-uniform
            __builtin_amdgcn_global_load_lds(
                (const __attribute__((address_space(1))) unsigned int*)(gbase + gb),
                (__attribute__((address_space(3))) unsigned int*)((char*)lB + ldsoff),
                16, 0, 0);
        }
    }

    // ---- prefetch ALL A fragments into registers (8 x short8 = 32 VGPR) ----
    short8 a[2][4];   // [mi][kk]
    {
        const unsigned short* Au =
            xbf + ((size_t)(moff + tbi * 128 + wr * 32 + l15) * D + g * 8);
        #pragma unroll
        for (int mi = 0; mi < 2; ++mi)
            #pragma unroll
            for (int kk = 0; kk < 4; ++kk)
                a[mi][kk] = *reinterpret_cast<const short8*>(Au + mi * 16 * D + kk * 32);
    }

    __syncthreads();   // drains gload_lds (vmcnt 0) and A prefetch together

    float4v accv[2][4] = {};

    #pragma unroll
    for (int kk = 0; kk < 4; ++kk) {
        short8 b[4];
        #pragma unroll
        for (int ni = 0; ni < 4; ++ni) {
            const int trow = wc * 64 + ni * 16 + l15;
            const int boff = (kk * 64 + g * 16) ^ ((trow & 7) << 4);
            b[ni] = *reinterpret_cast<short8*>(reinterpret_cast<char*>(lB) + trow * 256 + boff);
        }
        #pragma unroll
        for (int mi = 0; mi < 2; ++mi)
            #pragma unroll
            for (int ni = 0; ni < 4; ++ni)
                accv[mi][ni] = __builtin_amdgcn_mfma_f32_16x16x32_bf16(a[mi][kk], b[ni], accv[mi][ni], 0, 0, 0);
    }

    // ---- fused epilogue: acc += s * cubic(s), single accumulator ----
    const bool diag = (tbi == tbj);
    const int rbase = tbi * 128 + wr * 32;
    const int cbase = tbj * 128 + wc * 64;

    float xr1[8], xc[4];
    #pragma unroll
    for (int mi = 0; mi < 2; ++mi)
        #pragma unroll
        for (int r = 0; r < 4; ++r)
            xr1[mi * 4 + r] = xx[moff + rbase + mi * 16 + g * 4 + r] + 1.0f;  // fold +1 of d+1
    #pragma unroll
    for (int ni = 0; ni < 4; ++ni)
        xc[ni] = xx[moff + cbase + ni * 16 + l15];

    float acc0 = 0.0f, acc1 = 0.0f;
    #pragma unroll
    for (int mi = 0; mi < 2; ++mi) {
        #pragma unroll
        for (int ni = 0; ni < 4; ++ni) {
            #pragma unroll
            for (int r = 0; r < 4; ++r) {
                const float dot = accv[mi][ni][r];
                float t1 = xr1[mi * 4 + r] + xc[ni];
                float m = fmaxf(fmaf(dot, -2.0f, t1), 1.0f);   // max(d,0)+1
                float s = __builtin_amdgcn_rcpf(m);
                if (diag) {
                    const int row = rbase + mi * 16 + g * 4 + r;
                    const int col = cbase + ni * 16 + l15;
                    if (row == col) s = 0.0f;
                }
                float u = fmaf(s, C3, C2);
                u = fmaf(s, u, C1);
                u = fmaf(s, u, C0);
                if (r & 1) acc1 = fmaf(s, u, acc1);
                else       acc0 = fmaf(s, u, acc0);
            }
        }
    }
    float acc = acc0 + acc1;

    // ---- block reduction (single value) ----
    #pragma unroll
    for (int off = 32; off; off >>= 1) acc += __shfl_down(acc, off, 64);
    if (lane == 0) red[wave] = acc;
    __syncthreads();
    if (t == 0) {
        float S = 0.0f;
        #pragma unroll
        for (int w = 0; w < 8; ++w) S += red[w];
        const float w = diag ? 1.0f : 2.0f;
        atomicAdd(&negacc[(blockIdx.x * 2 + blockIdx.y) & (NACC - 1)], w * S);
    }
}

// ---- Kernel 3: final sum (64 neg slots + 256 prep partials) ----
__global__ void finish_kernel(const float* __restrict__ negacc,
                              const float* __restrict__ part,
                              float* __restrict__ out) {
    const int lane = threadIdx.x & 63;
    float v = negacc[lane];
    float pp = part[lane] + part[lane + 64] + part[lane + 128] + part[lane + 192];
    v = fmaf(pp, 1.0f / (float)BHALF, v);
    #pragma unroll
    for (int off = 32; off; off >>= 1) v += __shfl_down(v, off, 64);
    if (lane == 0) out[0] = v;
}

extern "C" void kernel_launch(void* const* d_in, const int* in_sizes, int n_in,
                              void* d_out, int out_size, void* d_ws, size_t ws_size,
                              hipStream_t stream) {
    const float* f = (const float*)d_in[0];
    float* out = (float*)d_out;
    unsigned short* xbf = (unsigned short*)d_ws;
    float* xx = (float*)((char*)d_ws + (size_t)NROWS * D * sizeof(unsigned short));
    float* negacc = xx + NROWS;
    float* part = negacc + NACC;

    prep_pos_kernel<<<NPART, 512, 0, stream>>>(f, xbf, xx, part, negacc);
    neg_kernel<<<dim3(NPAIRS, 2), 512, 0, stream>>>(xbf, xx, negacc);
    finish_kernel<<<1, 64, 0, stream>>>(negacc, part, out);
}